// Round 7
// baseline (202.384 us; speedup 1.0000x reference)
//
#include <hip/hip_runtime.h>
#include <stdint.h>

#define LOG2E 1.44269504088896340736f

using bf16x8 = __attribute__((ext_vector_type(8))) short;  // 8 bf16 (4 VGPRs)
using f32x4  = __attribute__((ext_vector_type(4))) float;

__device__ __forceinline__ ushort f2bf(float f) {
  union { float f; uint32_t u; } v; v.f = f;
  uint32_t u = v.u;
  u += 0x7FFFu + ((u >> 16) & 1u);   // RNE
  return (ushort)(u >> 16);
}
__device__ __forceinline__ float bf2f(ushort b) {
  union { uint32_t u; float f; } v; v.u = ((uint32_t)b) << 16;
  return v.f;
}
__device__ __forceinline__ uint32_t fbits(float x) {
  union { float f; uint32_t u; } v; v.f = x; return v.u;
}

__device__ __forceinline__ void load_lds16(const void* g, void* l) {
  __builtin_amdgcn_global_load_lds(
      (const __attribute__((address_space(1))) void*)g,
      (__attribute__((address_space(3))) void*)l, 16, 0, 0);
}

// out[row] = dot(mat[row, 0:512], vec[0:512]); 4 rows per 256-thread block
__global__ void rowdot(const float* __restrict__ mat, const float* __restrict__ vec,
                       float* __restrict__ out) {
  int w = threadIdx.x >> 6, l = threadIdx.x & 63;
  int row = blockIdx.x * 4 + w;
  const float4* mp = (const float4*)(mat + row * 512 + l * 8);
  const float4* vp = (const float4*)(vec + l * 8);
  float4 a0 = mp[0], a1 = mp[1];
  float4 b0 = vp[0], b1 = vp[1];
  float d = a0.x * b0.x + a0.y * b0.y + a0.z * b0.z + a0.w * b0.w
          + a1.x * b1.x + a1.y * b1.y + a1.z * b1.z + a1.w * b1.w;
#pragma unroll
  for (int o = 32; o > 0; o >>= 1) d += __shfl_xor(d, o, 64);
  if (l == 0) out[row] = d;
}

__global__ void reduce_max(const float* __restrict__ v, float* __restrict__ outmax) {
  __shared__ float red[4];
  int t = threadIdx.x;
  float m = -3.0e38f;
  for (int j = t; j < 8192; j += 256) m = fmaxf(m, v[j]);
#pragma unroll
  for (int o = 32; o > 0; o >>= 1) m = fmaxf(m, __shfl_xor(m, o, 64));
  if ((t & 63) == 0) red[t >> 6] = m;
  __syncthreads();
  if (t == 0) outmax[0] = fmaxf(fmaxf(red[0], red[1]), fmaxf(red[2], red[3]));
}

// E1[j] = exp2(sm[j]*L), E2[j] = exp2(0.2*sm[j]*L)  (8192 elems)
__global__ void exp_sm(const float* __restrict__ s_m, float* __restrict__ E1,
                       float* __restrict__ E2) {
  int j = blockIdx.x * 256 + threadIdx.x;
  float v = s_m[j];
  E1[j] = exp2f(v * LOG2E);
  E2[j] = exp2f(v * (0.2f * LOG2E));
}

__global__ void cvt4_bf16(const float* __restrict__ in, ushort* __restrict__ out) {
  int idx = blockIdx.x * 256 + threadIdx.x;
  float4 v = ((const float4*)in)[idx];
  ushort4 o; o.x = f2bf(v.x); o.y = f2bf(v.y); o.z = f2bf(v.z); o.w = f2bf(v.w);
  ((ushort4*)out)[idx] = o;
}

// wT_bf[f][c] = bf16(weight[c][f]); 512x512
__global__ void transpose_w(const float* __restrict__ w, ushort* __restrict__ wT) {
  __shared__ float tile[32][33];
  int t = threadIdx.x; int tx = t & 31, ty = t >> 5;
  int cb = (blockIdx.x & 15) * 32, fb = (blockIdx.x >> 4) * 32;
#pragma unroll
  for (int k = 0; k < 4; ++k) tile[ty + k * 8][tx] = w[(cb + ty + k * 8) * 512 + fb + tx];
  __syncthreads();
#pragma unroll
  for (int k = 0; k < 4; ++k) wT[(fb + ty + k * 8) * 512 + cb + tx] = f2bf(tile[tx][ty + k * 8]);
}

// Whm = neigh @ W, stored in MFMA-B-fragment-packed layout:
//   BP[((fb*256 + kc)*64 + lp)*8 + q] = Whm[j][f],
//   fb=f>>4, kc=j>>5, lp=(f&15)+16*((j&31)>>3), q=j&7
// so attn lane l reads its 16x32 B-frag as 16 contiguous bytes at slot l.
__global__ __launch_bounds__(256, 4) void gemm_whmT(const ushort* __restrict__ A,
                                                    const ushort* __restrict__ B,
                                                    ushort* __restrict__ BP) {
  __shared__ ushort At[128 * 32];
  __shared__ ushort Bt2[128 * 32];
  int t = threadIdx.x;
  int j0 = (blockIdx.x >> 2) * 128, f0 = (blockIdx.x & 3) * 128;
  int w = t >> 6, l = t & 63, wr = w >> 1, wc = w & 1;
  f32x4 acc[4][4] = {};
  for (int it = 0; it < 16; ++it) {
    int k0 = it * 32;
#pragma unroll
    for (int c = 0; c < 2; ++c) {
      int u = c * 256 + t; int rr = u >> 2, p = u & 3;
      int sg = p ^ ((rr >> 1) & 3);
      load_lds16(A + (j0 + rr) * 512 + k0 + sg * 8, At + (c * 256 + (t & ~63)) * 8);
      load_lds16(B + (f0 + rr) * 512 + k0 + sg * 8, Bt2 + (c * 256 + (t & ~63)) * 8);
    }
    __syncthreads();
    bf16x8 af[4], bfr[4];
#pragma unroll
    for (int m = 0; m < 4; ++m) {
      int rr = wr * 64 + m * 16 + (l & 15);
      int q = (l >> 4) ^ ((rr >> 1) & 3);
      af[m] = *(const bf16x8*)(At + rr * 32 + q * 8);
    }
#pragma unroll
    for (int n = 0; n < 4; ++n) {
      int rb = wc * 64 + n * 16 + (l & 15);
      int q = (l >> 4) ^ ((rb >> 1) & 3);
      bfr[n] = *(const bf16x8*)(Bt2 + rb * 32 + q * 8);
    }
#pragma unroll
    for (int m = 0; m < 4; ++m)
#pragma unroll
      for (int n = 0; n < 4; ++n)
        acc[m][n] = __builtin_amdgcn_mfma_f32_16x16x32_bf16(af[m], bfr[n], acc[m][n], 0, 0, 0);
    __syncthreads();
  }
#pragma unroll
  for (int m = 0; m < 4; ++m)
#pragma unroll
    for (int n = 0; n < 4; ++n) {
      int f  = f0 + wc * 64 + n * 16 + (l & 15);
      int j4 = j0 + wr * 64 + m * 16 + (l >> 4) * 4;   // 4 consecutive j
      size_t slot = ((size_t)(f >> 4) * 256 + (j4 >> 5)) * 64
                  + (f & 15) + 16 * ((j4 >> 3) & 3);
      ushort4 o;
      o.x = f2bf(acc[m][n][0]); o.y = f2bf(acc[m][n][1]);
      o.z = f2bf(acc[m][n][2]); o.w = f2bf(acc[m][n][3]);
      *(ushort4*)(BP + slot * 8 + (j4 & 7)) = o;
    }
}

// ---------------------------------------------------------------------------
// Main fused kernel v7: BARRIER-FREE. grid 1024 = 64 rblk x 8 ksplit x 2 fhalf,
// 256 threads = 4 waves. Each wave independently owns 64 rows x 64 f x 1024 k:
// computes its own P A-fragments in registers (P = mask ? max(A1_i*B1_j,
// A2_i*B2_j) : 0 -- exp hoisted out of the inner loop entirely), loads B
// fragments coalesced from the packed BP layout, accumulates 16 MFMA/body.
// No LDS, no s_barrier, no inline asm. Latency hidden by 3 waves/SIMD + deep
// per-wave VMEM pipelining (mask int4 slots self-renew with ~1-body flight).
// ---------------------------------------------------------------------------
__global__ __launch_bounds__(256, 3) void attn_main(
    const ushort* __restrict__ BP, const int* __restrict__ mask,
    const float* __restrict__ s_n, const float* __restrict__ E1,
    const float* __restrict__ E2, const float* __restrict__ smaxp,
    ushort* __restrict__ num, float* __restrict__ den) {
  int t = threadIdx.x;
  int bid = blockIdx.x;
  int s    = bid & 7;            // ksplit == XCD under round-robin
  int rblk = (bid >> 3) & 63;
  int fh   = bid >> 9;           // 0..1
  int l = t & 63, w = t >> 6;
  int fg = fh * 4 + w;           // f-group 0..7; f base = fg*64
  int i0 = rblk * 64;
  int kb = s * 1024, kc0 = s * 32;
  int l15 = l & 15, lq = l >> 4;

  // per-row factors: A1 = exp2((sn-mi)L), A2 = exp2((0.2sn-mi)L), mi=lrelu(sn+smax)
  float smx = smaxp[0];
  float A1[4], A2[4], dacc[4];
#pragma unroll
  for (int m = 0; m < 4; ++m) {
    float sn = s_n[i0 + l15 + 16 * m];
    float mz = sn + smx;
    float mi = fmaxf(mz, 0.2f * mz);
    A1[m] = exp2f((sn - mi) * LOG2E);
    A2[m] = exp2f((0.2f * sn - mi) * LOG2E);
    dacc[m] = 0.f;
  }

  const int* mbase = mask + (size_t)(i0 + l15) * 8192 + kb + lq * 8;  // + m*131072
  const float* e1p = E1 + kb + lq * 8;
  const float* e2p = E2 + kb + lq * 8;
  const ushort* bpb = BP + ((size_t)(fg * 4) * 256 + kc0) * 64 * 8 + l * 8;  // + n*131072 + it*512

  // prefetch body 0
  int4 mka[4], mkb[4];
#pragma unroll
  for (int m = 0; m < 4; ++m) {
    mka[m] = *(const int4*)(mbase + m * 131072);
    mkb[m] = *(const int4*)(mbase + m * 131072 + 4);
  }
  float4 e1a = *(const float4*)(e1p), e1b = *(const float4*)(e1p + 4);
  float4 e2a = *(const float4*)(e2p), e2b = *(const float4*)(e2p + 4);

  f32x4 acc[4][4] = {};
  union PkU { uint32_t u[4]; bf16x8 v; };

  for (int it = 0; it < 32; ++it) {
    // B fragments for this body (L2-resident packed chunks, fully coalesced)
    bf16x8 b0 = *(const bf16x8*)(bpb + 0 * 131072 + it * 512);
    bf16x8 b1 = *(const bf16x8*)(bpb + 1 * 131072 + it * 512);
    bf16x8 b2 = *(const bf16x8*)(bpb + 2 * 131072 + it * 512);
    bf16x8 b3 = *(const bf16x8*)(bpb + 3 * 131072 + it * 512);
    int itn = (it + 1) & 31;
#pragma unroll
    for (int m = 0; m < 4; ++m) {
      int4 ka = mka[m], kbv = mkb[m];
      float p0 = ka.x  ? fmaxf(A1[m] * e1a.x, A2[m] * e2a.x) : 0.f;
      float p1 = ka.y  ? fmaxf(A1[m] * e1a.y, A2[m] * e2a.y) : 0.f;
      float p2 = ka.z  ? fmaxf(A1[m] * e1a.z, A2[m] * e2a.z) : 0.f;
      float p3 = ka.w  ? fmaxf(A1[m] * e1a.w, A2[m] * e2a.w) : 0.f;
      float p4 = kbv.x ? fmaxf(A1[m] * e1b.x, A2[m] * e2b.x) : 0.f;
      float p5 = kbv.y ? fmaxf(A1[m] * e1b.y, A2[m] * e2b.y) : 0.f;
      float p6 = kbv.z ? fmaxf(A1[m] * e1b.z, A2[m] * e2b.z) : 0.f;
      float p7 = kbv.w ? fmaxf(A1[m] * e1b.w, A2[m] * e2b.w) : 0.f;
      // reissue this m-slot for next body (~1 body of flight)
      mka[m] = *(const int4*)(mbase + m * 131072 + itn * 32);
      mkb[m] = *(const int4*)(mbase + m * 131072 + itn * 32 + 4);
      if (fg == 0)
        dacc[m] += ((p0 + p1) + (p2 + p3)) + ((p4 + p5) + (p6 + p7));
      PkU pk;
      pk.u[0] = (fbits(p1) & 0xFFFF0000u) | (fbits(p0) >> 16);
      pk.u[1] = (fbits(p3) & 0xFFFF0000u) | (fbits(p2) >> 16);
      pk.u[2] = (fbits(p5) & 0xFFFF0000u) | (fbits(p4) >> 16);
      pk.u[3] = (fbits(p7) & 0xFFFF0000u) | (fbits(p6) >> 16);
      acc[m][0] = __builtin_amdgcn_mfma_f32_16x16x32_bf16(pk.v, b0, acc[m][0], 0, 0, 0);
      acc[m][1] = __builtin_amdgcn_mfma_f32_16x16x32_bf16(pk.v, b1, acc[m][1], 0, 0, 0);
      acc[m][2] = __builtin_amdgcn_mfma_f32_16x16x32_bf16(pk.v, b2, acc[m][2], 0, 0, 0);
      acc[m][3] = __builtin_amdgcn_mfma_f32_16x16x32_bf16(pk.v, b3, acc[m][3], 0, 0, 0);
    }
    // reissue e-tables for next body (64 KB, L2-hot)
    e1a = *(const float4*)(e1p + itn * 32);
    e1b = *(const float4*)(e1p + itn * 32 + 4);
    e2a = *(const float4*)(e2p + itn * 32);
    e2b = *(const float4*)(e2p + itn * 32 + 4);
  }

  // denominator (one wave per (s, rblk)): rows l15+16m, reduce across lq groups
  if (fg == 0) {
#pragma unroll
    for (int m = 0; m < 4; ++m) {
      float d = dacc[m];
      d += __shfl_xor(d, 16, 64);
      d += __shfl_xor(d, 32, 64);
      if (l < 16) den[s * 4096 + i0 + l + 16 * m] = d;
    }
  }
  // numerator write, packed [s][i>>2][512][i&3] bf16, 8B/lane dense lines
#pragma unroll
  for (int m = 0; m < 4; ++m)
#pragma unroll
    for (int n = 0; n < 4; ++n) {
      int ig = rblk * 16 + m * 4 + lq;
      int f = fg * 64 + n * 16 + l15;
      ushort4 o;
      o.x = f2bf(acc[m][n][0]); o.y = f2bf(acc[m][n][1]);
      o.z = f2bf(acc[m][n][2]); o.w = f2bf(acc[m][n][3]);
      *(ushort4*)(num + (((size_t)s * 1024 + ig) * 512 + f) * 4) = o;
    }
}

// out[ig*4+r][f] = (sum_s num[s][ig][f][r]) / (sum_s den[s][ig*4+r])
__global__ void reduce_out(const ushort* __restrict__ num, const float* __restrict__ den,
                           float* __restrict__ out) {
  int idx = blockIdx.x * 256 + threadIdx.x;  // 524288 threads
  int ig = idx >> 9, f = idx & 511;
  float s0 = 0.f, s1 = 0.f, s2 = 0.f, s3 = 0.f;
#pragma unroll
  for (int s = 0; s < 8; ++s) {
    ushort4 v = *(const ushort4*)(num + (((size_t)s * 1024 + ig) * 512 + f) * 4);
    s0 += bf2f(v.x); s1 += bf2f(v.y); s2 += bf2f(v.z); s3 += bf2f(v.w);
  }
  float d0 = 0.f, d1 = 0.f, d2 = 0.f, d3 = 0.f;
#pragma unroll
  for (int s = 0; s < 8; ++s) {
    const float* dp = den + s * 4096 + ig * 4;
    d0 += dp[0]; d1 += dp[1]; d2 += dp[2]; d3 += dp[3];
  }
  float* op = out + (size_t)ig * 4 * 512 + f;
  op[0]        = s0 / d0;
  op[512]      = s1 / d1;
  op[2 * 512]  = s2 / d2;
  op[3 * 512]  = s3 / d3;
}

extern "C" void kernel_launch(void* const* d_in, const int* in_sizes, int n_in,
                              void* d_out, int out_size, void* d_ws, size_t ws_size,
                              hipStream_t stream) {
  const float* node   = (const float*)d_in[0];
  const float* neigh  = (const float*)d_in[1];
  const float* weight = (const float*)d_in[2];
  const float* att    = (const float*)d_in[3];
  const int*   mask   = (const int*)d_in[4];
  float* out = (float*)d_out;

  char* ws = (char*)d_ws;
  float* w_a1 = (float*)ws;            // 512
  float* w_a2 = w_a1 + 512;            // 512
  float* s_n  = w_a2 + 512;            // 4096
  float* s_m  = s_n + 4096;            // 8192
  float* smax = s_m + 8192;            // 1
  ushort* neigh_bf = (ushort*)(ws + 64 * 1024);    // 8 MB
  ushort* wT_bf    = neigh_bf + 8192 * 512;        // 0.5 MB
  ushort* BP       = wT_bf + 512 * 512;            // 8 MB (fragment-packed Whm)
  ushort* num      = BP + 512 * 8192;              // 32 MB (bf16, packed)
  float*  den      = (float*)(num + (size_t)8 * 1024 * 512 * 4);  // 128 KB
  float*  E1       = den + 8 * 4096;               // 32 KB
  float*  E2       = E1 + 8192;                    // 32 KB

  rowdot<<<128, 256, 0, stream>>>(weight, att, w_a1);
  rowdot<<<128, 256, 0, stream>>>(weight, att + 512, w_a2);
  rowdot<<<1024, 256, 0, stream>>>(node, w_a1, s_n);
  rowdot<<<2048, 256, 0, stream>>>(neigh, w_a2, s_m);
  reduce_max<<<1, 256, 0, stream>>>(s_m, smax);
  exp_sm<<<32, 256, 0, stream>>>(s_m, E1, E2);
  cvt4_bf16<<<4096, 256, 0, stream>>>(neigh, neigh_bf);
  transpose_w<<<256, 256, 0, stream>>>(weight, wT_bf);
  gemm_whmT<<<256, 256, 0, stream>>>(neigh_bf, wT_bf, BP);
  attn_main<<<1024, 256, 0, stream>>>(BP, mask, s_n, E1, E2, smax, num, den);
  reduce_out<<<2048, 256, 0, stream>>>(num, den, out);
}

// Round 8
// 162.482 us; speedup vs baseline: 1.2456x; 1.2456x over previous
//
#include <hip/hip_runtime.h>
#include <stdint.h>

#define LOG2E 1.44269504088896340736f

using bf16x8 = __attribute__((ext_vector_type(8))) short;  // 8 bf16 (4 VGPRs)
using f32x4  = __attribute__((ext_vector_type(4))) float;

__device__ __forceinline__ ushort f2bf(float f) {
  union { float f; uint32_t u; } v; v.f = f;
  uint32_t u = v.u;
  u += 0x7FFFu + ((u >> 16) & 1u);   // RNE
  return (ushort)(u >> 16);
}
__device__ __forceinline__ float bf2f(ushort b) {
  union { uint32_t u; float f; } v; v.u = ((uint32_t)b) << 16;
  return v.f;
}

__device__ __forceinline__ void load_lds16(const void* g, void* l) {
  __builtin_amdgcn_global_load_lds(
      (const __attribute__((address_space(1))) void*)g,
      (__attribute__((address_space(3))) void*)l, 16, 0, 0);
}
__device__ __forceinline__ void load_lds4(const void* g, void* l) {
  __builtin_amdgcn_global_load_lds(
      (const __attribute__((address_space(1))) void*)g,
      (__attribute__((address_space(3))) void*)l, 4, 0, 0);
}

// out[row] = dot(mat[row, 0:512], vec[0:512]); 4 rows per 256-thread block
__global__ void rowdot(const float* __restrict__ mat, const float* __restrict__ vec,
                       float* __restrict__ out) {
  int w = threadIdx.x >> 6, l = threadIdx.x & 63;
  int row = blockIdx.x * 4 + w;
  const float4* mp = (const float4*)(mat + row * 512 + l * 8);
  const float4* vp = (const float4*)(vec + l * 8);
  float4 a0 = mp[0], a1 = mp[1];
  float4 b0 = vp[0], b1 = vp[1];
  float d = a0.x * b0.x + a0.y * b0.y + a0.z * b0.z + a0.w * b0.w
          + a1.x * b1.x + a1.y * b1.y + a1.z * b1.z + a1.w * b1.w;
#pragma unroll
  for (int o = 32; o > 0; o >>= 1) d += __shfl_xor(d, o, 64);
  if (l == 0) out[row] = d;
}

__global__ void reduce_max(const float* __restrict__ v, float* __restrict__ outmax) {
  __shared__ float red[4];
  int t = threadIdx.x;
  float m = -3.0e38f;
  for (int j = t; j < 8192; j += 256) m = fmaxf(m, v[j]);
#pragma unroll
  for (int o = 32; o > 0; o >>= 1) m = fmaxf(m, __shfl_xor(m, o, 64));
  if ((t & 63) == 0) red[t >> 6] = m;
  __syncthreads();
  if (t == 0) outmax[0] = fmaxf(fmaxf(red[0], red[1]), fmaxf(red[2], red[3]));
}

// E1[j] = exp2(sm[j]*L), E2[j] = exp2(0.2*sm[j]*L)
__global__ void exp_sm(const float* __restrict__ s_m, float* __restrict__ E1,
                       float* __restrict__ E2) {
  int j = blockIdx.x * 256 + threadIdx.x;
  float v = s_m[j];
  E1[j] = exp2f(v * LOG2E);
  E2[j] = exp2f(v * (0.2f * LOG2E));
}

// A1[i] = exp2((sn-mi)L), A2[i] = exp2((0.2sn-mi)L), mi = lrelu(sn+smax)
__global__ void comp_A(const float* __restrict__ s_n, const float* __restrict__ smaxp,
                       float* __restrict__ A1, float* __restrict__ A2) {
  int i = blockIdx.x * 256 + threadIdx.x;
  float sn = s_n[i];
  float mz = sn + smaxp[0];
  float mi = fmaxf(mz, 0.2f * mz);
  A1[i] = exp2f((sn - mi) * LOG2E);
  A2[i] = exp2f((0.2f * sn - mi) * LOG2E);
}

__global__ void cvt4_bf16(const float* __restrict__ in, ushort* __restrict__ out) {
  int idx = blockIdx.x * 256 + threadIdx.x;
  float4 v = ((const float4*)in)[idx];
  ushort4 o; o.x = f2bf(v.x); o.y = f2bf(v.y); o.z = f2bf(v.z); o.w = f2bf(v.w);
  ((ushort4*)out)[idx] = o;
}

// wT_bf[f][c] = bf16(weight[c][f]); 512x512
__global__ void transpose_w(const float* __restrict__ w, ushort* __restrict__ wT) {
  __shared__ float tile[32][33];
  int t = threadIdx.x; int tx = t & 31, ty = t >> 5;
  int cb = (blockIdx.x & 15) * 32, fb = (blockIdx.x >> 4) * 32;
#pragma unroll
  for (int k = 0; k < 4; ++k) tile[ty + k * 8][tx] = w[(cb + ty + k * 8) * 512 + fb + tx];
  __syncthreads();
#pragma unroll
  for (int k = 0; k < 4; ++k) wT[(fb + ty + k * 8) * 512 + cb + tx] = f2bf(tile[tx][ty + k * 8]);
}

// WhmT[f][j] = sum_c neigh_bf[j][c] * wT_bf[f][c]   (bf16 out, f-major)
__global__ __launch_bounds__(256, 4) void gemm_whmT(const ushort* __restrict__ A,
                                                    const ushort* __restrict__ B,
                                                    ushort* __restrict__ WhmT) {
  __shared__ ushort At[128 * 32];
  __shared__ ushort Bt2[128 * 32];
  int t = threadIdx.x;
  int j0 = (blockIdx.x >> 2) * 128, f0 = (blockIdx.x & 3) * 128;
  int w = t >> 6, l = t & 63, wr = w >> 1, wc = w & 1;
  f32x4 acc[4][4] = {};
  for (int it = 0; it < 16; ++it) {
    int k0 = it * 32;
#pragma unroll
    for (int c = 0; c < 2; ++c) {
      int u = c * 256 + t; int rr = u >> 2, p = u & 3;
      int sg = p ^ ((rr >> 1) & 3);
      load_lds16(A + (j0 + rr) * 512 + k0 + sg * 8, At + (c * 256 + (t & ~63)) * 8);
      load_lds16(B + (f0 + rr) * 512 + k0 + sg * 8, Bt2 + (c * 256 + (t & ~63)) * 8);
    }
    __syncthreads();
    bf16x8 af[4], bfr[4];
#pragma unroll
    for (int m = 0; m < 4; ++m) {
      int rr = wr * 64 + m * 16 + (l & 15);
      int q = (l >> 4) ^ ((rr >> 1) & 3);
      af[m] = *(const bf16x8*)(At + rr * 32 + q * 8);
    }
#pragma unroll
    for (int n = 0; n < 4; ++n) {
      int rb = wc * 64 + n * 16 + (l & 15);
      int q = (l >> 4) ^ ((rb >> 1) & 3);
      bfr[n] = *(const bf16x8*)(Bt2 + rb * 32 + q * 8);
    }
#pragma unroll
    for (int m = 0; m < 4; ++m)
#pragma unroll
      for (int n = 0; n < 4; ++n)
        acc[m][n] = __builtin_amdgcn_mfma_f32_16x16x32_bf16(af[m], bfr[n], acc[m][n], 0, 0, 0);
    __syncthreads();
  }
#pragma unroll
  for (int m = 0; m < 4; ++m)
#pragma unroll
    for (int n = 0; n < 4; ++n) {
      int j = j0 + wr * 64 + m * 16 + (l >> 4) * 4;
      int f = f0 + wc * 64 + n * 16 + (l & 15);
      ushort4 o;
      o.x = f2bf(acc[m][n][0]); o.y = f2bf(acc[m][n][1]);
      o.z = f2bf(acc[m][n][2]); o.w = f2bf(acc[m][n][3]);
      *(ushort4*)(WhmT + f * 8192 + j) = o;
    }
}

// ---------------------------------------------------------------------------
// Phase A: materialize P[4096][8192] bf16 row-major + row-sum partials.
// One block per row; 4 iterations x 2048 j. Pure streaming (mask 128MB in,
// P 64MB out); E/A tables L2-resident.
// ---------------------------------------------------------------------------
__global__ __launch_bounds__(256) void p_mat(
    const int* __restrict__ mask, const float* __restrict__ A1f,
    const float* __restrict__ A2f, const float* __restrict__ E1,
    const float* __restrict__ E2, ushort* __restrict__ P,
    float* __restrict__ den_part) {
  int row = blockIdx.x, t = threadIdx.x;
  float a1 = A1f[row], a2 = A2f[row];
  const int* mrow = mask + (size_t)row * 8192;
  ushort* prow = P + (size_t)row * 8192;
#pragma unroll
  for (int iter = 0; iter < 4; ++iter) {
    int j8 = (iter * 256 + t) * 8;
    int4 k0 = *(const int4*)(mrow + j8);
    int4 k1 = *(const int4*)(mrow + j8 + 4);
    float4 e1a = *(const float4*)(E1 + j8), e1b = *(const float4*)(E1 + j8 + 4);
    float4 e2a = *(const float4*)(E2 + j8), e2b = *(const float4*)(E2 + j8 + 4);
    float p0 = k0.x ? fmaxf(a1 * e1a.x, a2 * e2a.x) : 0.f;
    float p1 = k0.y ? fmaxf(a1 * e1a.y, a2 * e2a.y) : 0.f;
    float p2 = k0.z ? fmaxf(a1 * e1a.z, a2 * e2a.z) : 0.f;
    float p3 = k0.w ? fmaxf(a1 * e1a.w, a2 * e2a.w) : 0.f;
    float p4 = k1.x ? fmaxf(a1 * e1b.x, a2 * e2b.x) : 0.f;
    float p5 = k1.y ? fmaxf(a1 * e1b.y, a2 * e2b.y) : 0.f;
    float p6 = k1.z ? fmaxf(a1 * e1b.z, a2 * e2b.z) : 0.f;
    float p7 = k1.w ? fmaxf(a1 * e1b.w, a2 * e2b.w) : 0.f;
    ushort b0 = f2bf(p0), b1 = f2bf(p1), b2 = f2bf(p2), b3 = f2bf(p3);
    ushort b4 = f2bf(p4), b5 = f2bf(p5), b6 = f2bf(p6), b7 = f2bf(p7);
    uint4 pk;
    pk.x = ((uint32_t)b1 << 16) | b0;
    pk.y = ((uint32_t)b3 << 16) | b2;
    pk.z = ((uint32_t)b5 << 16) | b4;
    pk.w = ((uint32_t)b7 << 16) | b6;
    *(uint4*)(prow + j8) = pk;
    float d = ((bf2f(b0) + bf2f(b1)) + (bf2f(b2) + bf2f(b3)))
            + ((bf2f(b4) + bf2f(b5)) + (bf2f(b6) + bf2f(b7)));
#pragma unroll
    for (int o = 32; o > 0; o >>= 1) d += __shfl_xor(d, o, 64);
    if ((t & 63) == 0) den_part[row * 16 + iter * 4 + (t >> 6)] = d;
  }
}

// den[i] = sum of 16 partials
__global__ void p_den(const float* __restrict__ den_part, float* __restrict__ den) {
  int i = blockIdx.x * 256 + threadIdx.x;  // 4096
  const float* dp = den_part + i * 16;
  float d = 0.f;
#pragma unroll
  for (int k = 0; k < 16; ++k) d += dp[k];
  den[i] = d;
}

// ---------------------------------------------------------------------------
// Phase B: num[s] = P[:, s-slice] @ Whm[s-slice, :]. BM=64, BN=512, BK=32,
// ksplit=8 -> grid 512 (2 blk/CU, 16 waves/CU). Both tiles staged via
// global_load_lds (uniform 6 VMEM/thread/body -> counted vmcnt(6)), dbuf,
// 2 barriers/body, setprio around MFMA. No mask, no P-compute in loop.
// ---------------------------------------------------------------------------
__global__ __launch_bounds__(512, 4) void attn_gemm(
    const ushort* __restrict__ P, const ushort* __restrict__ WhmT,
    ushort* __restrict__ num) {
  __shared__ ushort Bt[2][512 * 32];  // 2 x 32 KB, xor-swizzled [f][32k]
  __shared__ ushort At[2][64 * 32];   // 2 x 4 KB, xor-swizzled [i][32k]
  int t = threadIdx.x;
  int bid = blockIdx.x;
  int s = bid & 7;           // ksplit == XCD under round-robin
  int rblk = bid >> 3;       // 0..63
  int i0 = rblk * 64;
  int kb = s * 1024;
  int w = t >> 6, l = t & 63, l15 = l & 15, lq = l >> 4;

  f32x4 acc[4][4] = {};

  // frag read bases; swizzle group q = lq ^ ((row>>1)&3), row%16 = l15 part
  int qA = lq ^ ((l15 >> 1) & 3);
  const ushort* pa0 = &At[0][0] + l15 * 32 + qA * 8;
  const ushort* pa1 = &At[1][0] + l15 * 32 + qA * 8;
  const ushort* pb0 = &Bt[0][0] + (w * 64 + l15) * 32 + qA * 8;
  const ushort* pb1 = &Bt[1][0] + (w * 64 + l15) * 32 + qA * 8;

#define STAGE_B(BUF_, T_)                                                     \
  {                                                                           \
    int k0_ = kb + (T_) * 32;                                                 \
    ushort* bb_ = BUF_;                                                       \
    _Pragma("unroll") for (int c = 0; c < 4; ++c) {                           \
      int u_ = c * 512 + t; int rr_ = u_ >> 2, p_ = u_ & 3;                   \
      int sg_ = p_ ^ ((rr_ >> 1) & 3);                                        \
      load_lds16(WhmT + rr_ * 8192 + k0_ + sg_ * 8,                           \
                 bb_ + (c * 512 + (t & ~63)) * 8);                            \
    }                                                                         \
  }
  // A tile 64x32 bf16 (4KB): 2 x 4B per thread, pre-swizzled source
#define STAGE_A(BUF_, T_)                                                     \
  {                                                                           \
    int k0_ = kb + (T_) * 32;                                                 \
    ushort* ab_ = BUF_;                                                       \
    _Pragma("unroll") for (int c = 0; c < 2; ++c) {                           \
      int u_ = c * 512 + t; int row_ = u_ >> 4, g_ = u_ & 15;                 \
      int col_ = (((g_ >> 2) ^ ((row_ >> 1) & 3)) << 3) + (g_ & 3) * 2;       \
      load_lds4(P + (size_t)(i0 + row_) * 8192 + k0_ + col_,                  \
                ab_ + (c * 512 + (t & ~63)) * 2);                             \
    }                                                                         \
  }

#define BODY(IT_, PA_, PB_, BN_, AN_, DO_STAGE, VMC_)                         \
  {                                                                           \
    if (DO_STAGE) { STAGE_B(BN_, (IT_) + 1); STAGE_A(AN_, (IT_) + 1); }       \
    asm volatile("s_waitcnt vmcnt(" #VMC_ ")" ::: "memory");                  \
    __builtin_amdgcn_s_barrier();                                             \
    bf16x8 af[4];                                                             \
    _Pragma("unroll") for (int m = 0; m < 4; ++m)                             \
      af[m] = *(const bf16x8*)(PA_ + m * 512);                                \
    __builtin_amdgcn_s_setprio(1);                                            \
    _Pragma("unroll") for (int n = 0; n < 4; ++n) {                           \
      bf16x8 bfr = *(const bf16x8*)(PB_ + n * 512);                           \
      _Pragma("unroll") for (int m = 0; m < 4; ++m)                           \
        acc[m][n] = __builtin_amdgcn_mfma_f32_16x16x32_bf16(af[m], bfr,       \
                                                            acc[m][n], 0, 0, 0); \
    }                                                                         \
    __builtin_amdgcn_s_setprio(0);                                            \
    asm volatile("s_barrier" ::: "memory");                                   \
  }

  // prologue
  STAGE_B(&Bt[0][0], 0);
  STAGE_A(&At[0][0], 0);
  asm volatile("s_waitcnt vmcnt(0)" ::: "memory");
  __builtin_amdgcn_s_barrier();

  for (int it2 = 0; it2 < 15; ++it2) {
    BODY(it2 * 2,     pa0, pb0, &Bt[1][0], &At[1][0], true, 6);
    BODY(it2 * 2 + 1, pa1, pb1, &Bt[0][0], &At[0][0], true, 6);
  }
  BODY(30, pa0, pb0, &Bt[1][0], &At[1][0], true, 6);
  BODY(31, pa1, pb1, &Bt[0][0], &At[0][0], false, 0);

  // numerator write, packed [s][i>>2][512][i&3] bf16, 8B/lane full lines
#pragma unroll
  for (int m = 0; m < 4; ++m)
#pragma unroll
    for (int n = 0; n < 4; ++n) {
      int ig = rblk * 16 + m * 4 + lq;
      int f = w * 64 + n * 16 + l15;
      ushort4 o;
      o.x = f2bf(acc[m][n][0]); o.y = f2bf(acc[m][n][1]);
      o.z = f2bf(acc[m][n][2]); o.w = f2bf(acc[m][n][3]);
      *(ushort4*)(num + (((size_t)s * 1024 + ig) * 512 + f) * 4) = o;
    }
#undef BODY
#undef STAGE_A
#undef STAGE_B
}

// out[ig*4+r][f] = (sum_s num[s][ig][f][r]) / den[ig*4+r]
__global__ void reduce_out(const ushort* __restrict__ num, const float* __restrict__ den,
                           float* __restrict__ out) {
  int idx = blockIdx.x * 256 + threadIdx.x;  // 524288 threads
  int ig = idx >> 9, f = idx & 511;
  float s0 = 0.f, s1 = 0.f, s2 = 0.f, s3 = 0.f;
#pragma unroll
  for (int s = 0; s < 8; ++s) {
    ushort4 v = *(const ushort4*)(num + (((size_t)s * 1024 + ig) * 512 + f) * 4);
    s0 += bf2f(v.x); s1 += bf2f(v.y); s2 += bf2f(v.z); s3 += bf2f(v.w);
  }
  const float* dp = den + ig * 4;
  float* op = out + (size_t)ig * 4 * 512 + f;
  op[0]       = s0 / dp[0];
  op[512]     = s1 / dp[1];
  op[2 * 512] = s2 / dp[2];
  op[3 * 512] = s3 / dp[3];
}

extern "C" void kernel_launch(void* const* d_in, const int* in_sizes, int n_in,
                              void* d_out, int out_size, void* d_ws, size_t ws_size,
                              hipStream_t stream) {
  const float* node   = (const float*)d_in[0];
  const float* neigh  = (const float*)d_in[1];
  const float* weight = (const float*)d_in[2];
  const float* att    = (const float*)d_in[3];
  const int*   mask   = (const int*)d_in[4];
  float* out = (float*)d_out;

  char* ws = (char*)d_ws;                       // needs ~105 MB
  float* fb = (float*)ws;
  float* w_a1    = fb;              // 512
  float* w_a2    = fb + 512;        // 512
  float* s_n     = fb + 1024;       // 4096
  float* s_m     = fb + 5120;       // 8192
  float* smax    = fb + 13312;      // 1
  float* A1      = fb + 13320;      // 4096
  float* A2      = fb + 17416;      // 4096
  float* E1      = fb + 21512;      // 8192
  float* E2      = fb + 29704;      // 8192
  float* den_part= fb + 37896;      // 65536
  float* den     = fb + 103432;     // 4096  (ends ~430KB)
  ushort* wT_bf  = (ushort*)(ws + 512 * 1024);             // 0.5 MB
  ushort* WhmT   = (ushort*)(ws + 1 * 1024 * 1024);        // 8 MB
  ushort* num    = (ushort*)(ws + 9 * 1024 * 1024);        // 32 MB
  ushort* P      = (ushort*)(ws + 41 * 1024 * 1024);       // 64 MB
  ushort* neigh_bf = P;   // first 8 MB of P region; consumed before p_mat runs

  rowdot<<<128, 256, 0, stream>>>(weight, att, w_a1);
  rowdot<<<128, 256, 0, stream>>>(weight, att + 512, w_a2);
  rowdot<<<1024, 256, 0, stream>>>(node, w_a1, s_n);
  rowdot<<<2048, 256, 0, stream>>>(neigh, w_a2, s_m);
  reduce_max<<<1, 256, 0, stream>>>(s_m, smax);
  exp_sm<<<32, 256, 0, stream>>>(s_m, E1, E2);
  comp_A<<<16, 256, 0, stream>>>(s_n, smax, A1, A2);
  cvt4_bf16<<<4096, 256, 0, stream>>>(neigh, neigh_bf);
  transpose_w<<<256, 256, 0, stream>>>(weight, wT_bf);
  gemm_whmT<<<256, 256, 0, stream>>>(neigh_bf, wT_bf, WhmT);
  p_mat<<<4096, 256, 0, stream>>>(mask, A1, A2, E1, E2, P, den_part);
  p_den<<<16, 256, 0, stream>>>(den_part, den);
  attn_gemm<<<512, 512, 0, stream>>>(P, WhmT, num);
  reduce_out<<<2048, 256, 0, stream>>>(num, den, out);
}

// Round 10
// 157.959 us; speedup vs baseline: 1.2812x; 1.0286x over previous
//
#include <hip/hip_runtime.h>
#include <stdint.h>

#define LOG2E 1.44269504088896340736f

using bf16x8 = __attribute__((ext_vector_type(8))) short;  // 8 bf16 (4 VGPRs)
using f32x4  = __attribute__((ext_vector_type(4))) float;

__device__ __forceinline__ ushort f2bf(float f) {
  union { float f; uint32_t u; } v; v.f = f;
  uint32_t u = v.u;
  u += 0x7FFFu + ((u >> 16) & 1u);   // RNE
  return (ushort)(u >> 16);
}
__device__ __forceinline__ float bf2f(ushort b) {
  union { uint32_t u; float f; } v; v.u = ((uint32_t)b) << 16;
  return v.f;
}

__device__ __forceinline__ void load_lds16(const void* g, void* l) {
  __builtin_amdgcn_global_load_lds(
      (const __attribute__((address_space(1))) void*)g,
      (__attribute__((address_space(3))) void*)l, 16, 0, 0);
}
__device__ __forceinline__ void load_lds4(const void* g, void* l) {
  __builtin_amdgcn_global_load_lds(
      (const __attribute__((address_space(1))) void*)g,
      (__attribute__((address_space(3))) void*)l, 4, 0, 0);
}

// out[row] = dot(mat[row, 0:512], vec[0:512]); 4 rows per 256-thread block
__global__ void rowdot(const float* __restrict__ mat, const float* __restrict__ vec,
                       float* __restrict__ out) {
  int w = threadIdx.x >> 6, l = threadIdx.x & 63;
  int row = blockIdx.x * 4 + w;
  const float4* mp = (const float4*)(mat + row * 512 + l * 8);
  const float4* vp = (const float4*)(vec + l * 8);
  float4 a0 = mp[0], a1 = mp[1];
  float4 b0 = vp[0], b1 = vp[1];
  float d = a0.x * b0.x + a0.y * b0.y + a0.z * b0.z + a0.w * b0.w
          + a1.x * b1.x + a1.y * b1.y + a1.z * b1.z + a1.w * b1.w;
#pragma unroll
  for (int o = 32; o > 0; o >>= 1) d += __shfl_xor(d, o, 64);
  if (l == 0) out[row] = d;
}

__global__ void reduce_max(const float* __restrict__ v, float* __restrict__ outmax) {
  __shared__ float red[4];
  int t = threadIdx.x;
  float m = -3.0e38f;
  for (int j = t; j < 8192; j += 256) m = fmaxf(m, v[j]);
#pragma unroll
  for (int o = 32; o > 0; o >>= 1) m = fmaxf(m, __shfl_xor(m, o, 64));
  if ((t & 63) == 0) red[t >> 6] = m;
  __syncthreads();
  if (t == 0) outmax[0] = fmaxf(fmaxf(red[0], red[1]), fmaxf(red[2], red[3]));
}

// E1[j] = exp2(sm[j]*L), E2[j] = exp2(0.2*sm[j]*L)
__global__ void exp_sm(const float* __restrict__ s_m, float* __restrict__ E1,
                       float* __restrict__ E2) {
  int j = blockIdx.x * 256 + threadIdx.x;
  float v = s_m[j];
  E1[j] = exp2f(v * LOG2E);
  E2[j] = exp2f(v * (0.2f * LOG2E));
}

// A1[i] = exp2((sn-mi)L), A2[i] = exp2((0.2sn-mi)L), mi = lrelu(sn+smax)
__global__ void comp_A(const float* __restrict__ s_n, const float* __restrict__ smaxp,
                       float* __restrict__ A1, float* __restrict__ A2) {
  int i = blockIdx.x * 256 + threadIdx.x;
  float sn = s_n[i];
  float mz = sn + smaxp[0];
  float mi = fmaxf(mz, 0.2f * mz);
  A1[i] = exp2f((sn - mi) * LOG2E);
  A2[i] = exp2f((0.2f * sn - mi) * LOG2E);
}

__global__ void cvt4_bf16(const float* __restrict__ in, ushort* __restrict__ out) {
  int idx = blockIdx.x * 256 + threadIdx.x;
  float4 v = ((const float4*)in)[idx];
  ushort4 o; o.x = f2bf(v.x); o.y = f2bf(v.y); o.z = f2bf(v.z); o.w = f2bf(v.w);
  ((ushort4*)out)[idx] = o;
}

// wT_bf[f][c] = bf16(weight[c][f]); 512x512
__global__ void transpose_w(const float* __restrict__ w, ushort* __restrict__ wT) {
  __shared__ float tile[32][33];
  int t = threadIdx.x; int tx = t & 31, ty = t >> 5;
  int cb = (blockIdx.x & 15) * 32, fb = (blockIdx.x >> 4) * 32;
#pragma unroll
  for (int k = 0; k < 4; ++k) tile[ty + k * 8][tx] = w[(cb + ty + k * 8) * 512 + fb + tx];
  __syncthreads();
#pragma unroll
  for (int k = 0; k < 4; ++k) wT[(fb + ty + k * 8) * 512 + cb + tx] = f2bf(tile[tx][ty + k * 8]);
}

// WhmT[f][j] = sum_c neigh_bf[j][c] * wT_bf[f][c]   (bf16 out, f-major)
__global__ __launch_bounds__(256, 4) void gemm_whmT(const ushort* __restrict__ A,
                                                    const ushort* __restrict__ B,
                                                    ushort* __restrict__ WhmT) {
  __shared__ ushort At[128 * 32];
  __shared__ ushort Bt2[128 * 32];
  int t = threadIdx.x;
  int j0 = (blockIdx.x >> 2) * 128, f0 = (blockIdx.x & 3) * 128;
  int w = t >> 6, l = t & 63, wr = w >> 1, wc = w & 1;
  f32x4 acc[4][4] = {};
  for (int it = 0; it < 16; ++it) {
    int k0 = it * 32;
#pragma unroll
    for (int c = 0; c < 2; ++c) {
      int u = c * 256 + t; int rr = u >> 2, p = u & 3;
      int sg = p ^ ((rr >> 1) & 3);
      load_lds16(A + (j0 + rr) * 512 + k0 + sg * 8, At + (c * 256 + (t & ~63)) * 8);
      load_lds16(B + (f0 + rr) * 512 + k0 + sg * 8, Bt2 + (c * 256 + (t & ~63)) * 8);
    }
    __syncthreads();
    bf16x8 af[4], bfr[4];
#pragma unroll
    for (int m = 0; m < 4; ++m) {
      int rr = wr * 64 + m * 16 + (l & 15);
      int q = (l >> 4) ^ ((rr >> 1) & 3);
      af[m] = *(const bf16x8*)(At + rr * 32 + q * 8);
    }
#pragma unroll
    for (int n = 0; n < 4; ++n) {
      int rb = wc * 64 + n * 16 + (l & 15);
      int q = (l >> 4) ^ ((rb >> 1) & 3);
      bfr[n] = *(const bf16x8*)(Bt2 + rb * 32 + q * 8);
    }
#pragma unroll
    for (int m = 0; m < 4; ++m)
#pragma unroll
      for (int n = 0; n < 4; ++n)
        acc[m][n] = __builtin_amdgcn_mfma_f32_16x16x32_bf16(af[m], bfr[n], acc[m][n], 0, 0, 0);
    __syncthreads();
  }
#pragma unroll
  for (int m = 0; m < 4; ++m)
#pragma unroll
    for (int n = 0; n < 4; ++n) {
      int j = j0 + wr * 64 + m * 16 + (l >> 4) * 4;
      int f = f0 + wc * 64 + n * 16 + (l & 15);
      ushort4 o;
      o.x = f2bf(acc[m][n][0]); o.y = f2bf(acc[m][n][1]);
      o.z = f2bf(acc[m][n][2]); o.w = f2bf(acc[m][n][3]);
      *(ushort4*)(WhmT + f * 8192 + j) = o;
    }
}

// ---------------------------------------------------------------------------
// Phase A v3: P[4096][8192] bf16 + row-sum. One block (256 thr) per row,
// 4 chunks x 2048 j (= exactly 8192). ALL mask loads issued upfront
// (8 int4/thread in flight); no in-loop cross-lane ops; one reduce at end.
// ---------------------------------------------------------------------------
__global__ __launch_bounds__(256, 6) void p_mat(
    const int* __restrict__ mask, const float* __restrict__ A1f,
    const float* __restrict__ A2f, const float* __restrict__ E1,
    const float* __restrict__ E2, ushort* __restrict__ P,
    float* __restrict__ den_part) {
  int row = blockIdx.x, t = threadIdx.x;
  float a1 = A1f[row], a2 = A2f[row];
  const int* mrow = mask + (size_t)row * 8192;
  ushort* prow = P + (size_t)row * 8192;
  float dacc = 0.f;

  int4 mk0[2], mk1[2], mk2[2], mk3[2];
#define LD(C_, MKD_)                                                         \
  { const int* lp_ = mrow + ((C_) * 256 + t) * 8;                            \
    MKD_[0] = *(const int4*)lp_; MKD_[1] = *(const int4*)(lp_ + 4); }

#define CHUNK(C_, MKD_)                                                      \
  {                                                                          \
    int j8_ = ((C_) * 256 + t) * 8;                                          \
    float4 e1a = *(const float4*)(E1 + j8_);                                 \
    float4 e1b = *(const float4*)(E1 + j8_ + 4);                             \
    float4 e2a = *(const float4*)(E2 + j8_);                                 \
    float4 e2b = *(const float4*)(E2 + j8_ + 4);                             \
    int4 k0_ = MKD_[0], k1_ = MKD_[1];                                       \
    float p0 = k0_.x ? fmaxf(a1 * e1a.x, a2 * e2a.x) : 0.f;                  \
    float p1 = k0_.y ? fmaxf(a1 * e1a.y, a2 * e2a.y) : 0.f;                  \
    float p2 = k0_.z ? fmaxf(a1 * e1a.z, a2 * e2a.z) : 0.f;                  \
    float p3 = k0_.w ? fmaxf(a1 * e1a.w, a2 * e2a.w) : 0.f;                  \
    float p4 = k1_.x ? fmaxf(a1 * e1b.x, a2 * e2b.x) : 0.f;                  \
    float p5 = k1_.y ? fmaxf(a1 * e1b.y, a2 * e2b.y) : 0.f;                  \
    float p6 = k1_.z ? fmaxf(a1 * e1b.z, a2 * e2b.z) : 0.f;                  \
    float p7 = k1_.w ? fmaxf(a1 * e1b.w, a2 * e2b.w) : 0.f;                  \
    ushort b0 = f2bf(p0), b1 = f2bf(p1), b2 = f2bf(p2), b3 = f2bf(p3);       \
    ushort b4 = f2bf(p4), b5 = f2bf(p5), b6 = f2bf(p6), b7 = f2bf(p7);       \
    uint4 pk;                                                                \
    pk.x = ((uint32_t)b1 << 16) | b0;                                        \
    pk.y = ((uint32_t)b3 << 16) | b2;                                        \
    pk.z = ((uint32_t)b5 << 16) | b4;                                        \
    pk.w = ((uint32_t)b7 << 16) | b6;                                        \
    *(uint4*)(prow + j8_) = pk;                                              \
    dacc += ((bf2f(b0) + bf2f(b1)) + (bf2f(b2) + bf2f(b3)))                  \
          + ((bf2f(b4) + bf2f(b5)) + (bf2f(b6) + bf2f(b7)));                 \
  }

  LD(0, mk0) LD(1, mk1) LD(2, mk2) LD(3, mk3)
  CHUNK(0, mk0) CHUNK(1, mk1) CHUNK(2, mk2) CHUNK(3, mk3)
#undef CHUNK
#undef LD

  // single end-of-kernel reduce: 4 partials per row (one per wave)
#pragma unroll
  for (int o = 32; o > 0; o >>= 1) dacc += __shfl_xor(dacc, o, 64);
  if ((t & 63) == 0) den_part[row * 4 + (t >> 6)] = dacc;
}

// den[i] = sum of 4 partials
__global__ void p_den(const float* __restrict__ den_part, float* __restrict__ den) {
  int i = blockIdx.x * 256 + threadIdx.x;  // 4096
  const float* dp = den_part + i * 4;
  den[i] = (dp[0] + dp[1]) + (dp[2] + dp[3]);
}

// ---------------------------------------------------------------------------
// Phase B: num[s] = P[:, s-slice] @ Whm[s-slice, :]. BM=64, BN=512, BK=32,
// ksplit=8 -> grid 512 (2 blk/CU). global_load_lds staging (6 VMEM/thread ->
// counted vmcnt(6)), dbuf, 2 barriers/body, setprio on MFMA.
// ---------------------------------------------------------------------------
__global__ __launch_bounds__(512, 4) void attn_gemm(
    const ushort* __restrict__ P, const ushort* __restrict__ WhmT,
    ushort* __restrict__ num) {
  __shared__ ushort Bt[2][512 * 32];  // 2 x 32 KB, xor-swizzled [f][32k]
  __shared__ ushort At[2][64 * 32];   // 2 x 4 KB, xor-swizzled [i][32k]
  int t = threadIdx.x;
  int bid = blockIdx.x;
  int s = bid & 7;           // ksplit == XCD under round-robin
  int rblk = bid >> 3;       // 0..63
  int i0 = rblk * 64;
  int kb = s * 1024;
  int w = t >> 6, l = t & 63, l15 = l & 15, lq = l >> 4;

  f32x4 acc[4][4] = {};

  int qA = lq ^ ((l15 >> 1) & 3);
  const ushort* pa0 = &At[0][0] + l15 * 32 + qA * 8;
  const ushort* pa1 = &At[1][0] + l15 * 32 + qA * 8;
  const ushort* pb0 = &Bt[0][0] + (w * 64 + l15) * 32 + qA * 8;
  const ushort* pb1 = &Bt[1][0] + (w * 64 + l15) * 32 + qA * 8;

#define STAGE_B(BUF_, T_)                                                     \
  {                                                                           \
    int k0_ = kb + (T_) * 32;                                                 \
    ushort* bb_ = BUF_;                                                       \
    _Pragma("unroll") for (int c = 0; c < 4; ++c) {                           \
      int u_ = c * 512 + t; int rr_ = u_ >> 2, p_ = u_ & 3;                   \
      int sg_ = p_ ^ ((rr_ >> 1) & 3);                                        \
      load_lds16(WhmT + rr_ * 8192 + k0_ + sg_ * 8,                           \
                 bb_ + (c * 512 + (t & ~63)) * 8);                            \
    }                                                                         \
  }
#define STAGE_A(BUF_, T_)                                                     \
  {                                                                           \
    int k0_ = kb + (T_) * 32;                                                 \
    ushort* ab_ = BUF_;                                                       \
    _Pragma("unroll") for (int c = 0; c < 2; ++c) {                           \
      int u_ = c * 512 + t; int row_ = u_ >> 4, g_ = u_ & 15;                 \
      int col_ = (((g_ >> 2) ^ ((row_ >> 1) & 3)) << 3) + (g_ & 3) * 2;       \
      load_lds4(P + (size_t)(i0 + row_) * 8192 + k0_ + col_,                  \
                ab_ + (c * 512 + (t & ~63)) * 2);                             \
    }                                                                         \
  }

#define BODY(IT_, PA_, PB_, BN_, AN_, DO_STAGE, VMC_)                         \
  {                                                                           \
    if (DO_STAGE) { STAGE_B(BN_, (IT_) + 1); STAGE_A(AN_, (IT_) + 1); }       \
    asm volatile("s_waitcnt vmcnt(" #VMC_ ")" ::: "memory");                  \
    __builtin_amdgcn_s_barrier();                                             \
    bf16x8 af[4];                                                             \
    _Pragma("unroll") for (int m = 0; m < 4; ++m)                             \
      af[m] = *(const bf16x8*)(PA_ + m * 512);                                \
    __builtin_amdgcn_s_setprio(1);                                            \
    _Pragma("unroll") for (int n = 0; n < 4; ++n) {                           \
      bf16x8 bfr = *(const bf16x8*)(PB_ + n * 512);                           \
      _Pragma("unroll") for (int m = 0; m < 4; ++m)                           \
        acc[m][n] = __builtin_amdgcn_mfma_f32_16x16x32_bf16(af[m], bfr,       \
                                                            acc[m][n], 0, 0, 0); \
    }                                                                         \
    __builtin_amdgcn_s_setprio(0);                                            \
    asm volatile("s_barrier" ::: "memory");                                   \
  }

  STAGE_B(&Bt[0][0], 0);
  STAGE_A(&At[0][0], 0);
  asm volatile("s_waitcnt vmcnt(0)" ::: "memory");
  __builtin_amdgcn_s_barrier();

  for (int it2 = 0; it2 < 15; ++it2) {
    BODY(it2 * 2,     pa0, pb0, &Bt[1][0], &At[1][0], true, 6);
    BODY(it2 * 2 + 1, pa1, pb1, &Bt[0][0], &At[0][0], true, 6);
  }
  BODY(30, pa0, pb0, &Bt[1][0], &At[1][0], true, 6);
  BODY(31, pa1, pb1, &Bt[0][0], &At[0][0], false, 0);

  // numerator write, packed [s][i>>2][512][i&3] bf16, 8B/lane full lines
#pragma unroll
  for (int m = 0; m < 4; ++m)
#pragma unroll
    for (int n = 0; n < 4; ++n) {
      int ig = rblk * 16 + m * 4 + lq;
      int f = w * 64 + n * 16 + l15;
      ushort4 o;
      o.x = f2bf(acc[m][n][0]); o.y = f2bf(acc[m][n][1]);
      o.z = f2bf(acc[m][n][2]); o.w = f2bf(acc[m][n][3]);
      *(ushort4*)(num + (((size_t)s * 1024 + ig) * 512 + f) * 4) = o;
    }
#undef BODY
#undef STAGE_A
#undef STAGE_B
}

// out[ig*4+r][f] = (sum_s num[s][ig][f][r]) / den[ig*4+r]
__global__ void reduce_out(const ushort* __restrict__ num, const float* __restrict__ den,
                           float* __restrict__ out) {
  int idx = blockIdx.x * 256 + threadIdx.x;  // 524288 threads
  int ig = idx >> 9, f = idx & 511;
  float s0 = 0.f, s1 = 0.f, s2 = 0.f, s3 = 0.f;
#pragma unroll
  for (int s = 0; s < 8; ++s) {
    ushort4 v = *(const ushort4*)(num + (((size_t)s * 1024 + ig) * 512 + f) * 4);
    s0 += bf2f(v.x); s1 += bf2f(v.y); s2 += bf2f(v.z); s3 += bf2f(v.w);
  }
  const float* dp = den + ig * 4;
  float* op = out + (size_t)ig * 4 * 512 + f;
  op[0]       = s0 / dp[0];
  op[512]     = s1 / dp[1];
  op[2 * 512] = s2 / dp[2];
  op[3 * 512] = s3 / dp[3];
}

extern "C" void kernel_launch(void* const* d_in, const int* in_sizes, int n_in,
                              void* d_out, int out_size, void* d_ws, size_t ws_size,
                              hipStream_t stream) {
  const float* node   = (const float*)d_in[0];
  const float* neigh  = (const float*)d_in[1];
  const float* weight = (const float*)d_in[2];
  const float* att    = (const float*)d_in[3];
  const int*   mask   = (const int*)d_in[4];
  float* out = (float*)d_out;

  char* ws = (char*)d_ws;                       // needs ~105 MB
  float* fb = (float*)ws;
  float* w_a1    = fb;              // 512
  float* w_a2    = fb + 512;        // 512
  float* s_n     = fb + 1024;       // 4096
  float* s_m     = fb + 5120;       // 8192
  float* smax    = fb + 13312;      // 1
  float* A1      = fb + 13320;      // 4096
  float* A2      = fb + 17416;      // 4096
  float* E1      = fb + 21512;      // 8192
  float* E2      = fb + 29704;      // 8192
  float* den_part= fb + 37896;      // 16384
  float* den     = fb + 54280;      // 4096
  ushort* wT_bf  = (ushort*)(ws + 512 * 1024);             // 0.5 MB
  ushort* WhmT   = (ushort*)(ws + 1 * 1024 * 1024);        // 8 MB
  ushort* num    = (ushort*)(ws + 9 * 1024 * 1024);        // 32 MB
  ushort* P      = (ushort*)(ws + 41 * 1024 * 1024);       // 64 MB
  ushort* neigh_bf = P;   // first 8 MB of P region; consumed before p_mat runs

  rowdot<<<128, 256, 0, stream>>>(weight, att, w_a1);
  rowdot<<<128, 256, 0, stream>>>(weight, att + 512, w_a2);
  rowdot<<<1024, 256, 0, stream>>>(node, w_a1, s_n);
  rowdot<<<2048, 256, 0, stream>>>(neigh, w_a2, s_m);
  reduce_max<<<1, 256, 0, stream>>>(s_m, smax);
  exp_sm<<<32, 256, 0, stream>>>(s_m, E1, E2);
  comp_A<<<16, 256, 0, stream>>>(s_n, smax, A1, A2);
  cvt4_bf16<<<4096, 256, 0, stream>>>(neigh, neigh_bf);
  transpose_w<<<256, 256, 0, stream>>>(weight, wT_bf);
  gemm_whmT<<<256, 256, 0, stream>>>(neigh_bf, wT_bf, WhmT);
  p_mat<<<4096, 256, 0, stream>>>(mask, A1, A2, E1, E2, P, den_part);
  p_den<<<16, 256, 0, stream>>>(den_part, den);
  attn_gemm<<<512, 512, 0, stream>>>(P, WhmT, num);
  reduce_out<<<2048, 256, 0, stream>>>(num, den, out);
}

// Round 11
// 142.981 us; speedup vs baseline: 1.4155x; 1.1048x over previous
//
#include <hip/hip_runtime.h>
#include <stdint.h>

#define LOG2E 1.44269504088896340736f

using bf16x8 = __attribute__((ext_vector_type(8))) short;  // 8 bf16 (4 VGPRs)
using f32x4  = __attribute__((ext_vector_type(4))) float;

__device__ __forceinline__ ushort f2bf(float f) {
  union { float f; uint32_t u; } v; v.f = f;
  uint32_t u = v.u;
  u += 0x7FFFu + ((u >> 16) & 1u);   // RNE
  return (ushort)(u >> 16);
}
__device__ __forceinline__ float bf2f(ushort b) {
  union { uint32_t u; float f; } v; v.u = ((uint32_t)b) << 16;
  return v.f;
}

__device__ __forceinline__ void load_lds16(const void* g, void* l) {
  __builtin_amdgcn_global_load_lds(
      (const __attribute__((address_space(1))) void*)g,
      (__attribute__((address_space(3))) void*)l, 16, 0, 0);
}

// out[row] = dot(mat[row, 0:512], vec[0:512]); 4 rows per 256-thread block
__global__ void rowdot(const float* __restrict__ mat, const float* __restrict__ vec,
                       float* __restrict__ out) {
  int w = threadIdx.x >> 6, l = threadIdx.x & 63;
  int row = blockIdx.x * 4 + w;
  const float4* mp = (const float4*)(mat + row * 512 + l * 8);
  const float4* vp = (const float4*)(vec + l * 8);
  float4 a0 = mp[0], a1 = mp[1];
  float4 b0 = vp[0], b1 = vp[1];
  float d = a0.x * b0.x + a0.y * b0.y + a0.z * b0.z + a0.w * b0.w
          + a1.x * b1.x + a1.y * b1.y + a1.z * b1.z + a1.w * b1.w;
#pragma unroll
  for (int o = 32; o > 0; o >>= 1) d += __shfl_xor(d, o, 64);
  if (l == 0) out[row] = d;
}

__global__ void reduce_max(const float* __restrict__ v, float* __restrict__ outmax) {
  __shared__ float red[4];
  int t = threadIdx.x;
  float m = -3.0e38f;
  for (int j = t; j < 8192; j += 256) m = fmaxf(m, v[j]);
#pragma unroll
  for (int o = 32; o > 0; o >>= 1) m = fmaxf(m, __shfl_xor(m, o, 64));
  if ((t & 63) == 0) red[t >> 6] = m;
  __syncthreads();
  if (t == 0) outmax[0] = fmaxf(fmaxf(red[0], red[1]), fmaxf(red[2], red[3]));
}

// E1[j] = exp2(sm[j]*L), E2[j] = exp2(0.2*sm[j]*L)
__global__ void exp_sm(const float* __restrict__ s_m, float* __restrict__ E1,
                       float* __restrict__ E2) {
  int j = blockIdx.x * 256 + threadIdx.x;
  float v = s_m[j];
  E1[j] = exp2f(v * LOG2E);
  E2[j] = exp2f(v * (0.2f * LOG2E));
}

// A1[i] = exp2((sn-mi)L), A2[i] = exp2((0.2sn-mi)L), mi = lrelu(sn+smax)
__global__ void comp_A(const float* __restrict__ s_n, const float* __restrict__ smaxp,
                       float* __restrict__ A1, float* __restrict__ A2) {
  int i = blockIdx.x * 256 + threadIdx.x;
  float sn = s_n[i];
  float mz = sn + smaxp[0];
  float mi = fmaxf(mz, 0.2f * mz);
  A1[i] = exp2f((sn - mi) * LOG2E);
  A2[i] = exp2f((0.2f * sn - mi) * LOG2E);
}

__global__ void cvt4_bf16(const float* __restrict__ in, ushort* __restrict__ out) {
  int idx = blockIdx.x * 256 + threadIdx.x;
  float4 v = ((const float4*)in)[idx];
  ushort4 o; o.x = f2bf(v.x); o.y = f2bf(v.y); o.z = f2bf(v.z); o.w = f2bf(v.w);
  ((ushort4*)out)[idx] = o;
}

// wT_bf[f][c] = bf16(weight[c][f]); 512x512
__global__ void transpose_w(const float* __restrict__ w, ushort* __restrict__ wT) {
  __shared__ float tile[32][33];
  int t = threadIdx.x; int tx = t & 31, ty = t >> 5;
  int cb = (blockIdx.x & 15) * 32, fb = (blockIdx.x >> 4) * 32;
#pragma unroll
  for (int k = 0; k < 4; ++k) tile[ty + k * 8][tx] = w[(cb + ty + k * 8) * 512 + fb + tx];
  __syncthreads();
#pragma unroll
  for (int k = 0; k < 4; ++k) wT[(fb + ty + k * 8) * 512 + cb + tx] = f2bf(tile[tx][ty + k * 8]);
}

// WhmT[f][j] = sum_c neigh_bf[j][c] * wT_bf[f][c]   (bf16 out, f-major)
__global__ __launch_bounds__(256, 4) void gemm_whmT(const ushort* __restrict__ A,
                                                    const ushort* __restrict__ B,
                                                    ushort* __restrict__ WhmT) {
  __shared__ ushort At[128 * 32];
  __shared__ ushort Bt2[128 * 32];
  int t = threadIdx.x;
  int j0 = (blockIdx.x >> 2) * 128, f0 = (blockIdx.x & 3) * 128;
  int w = t >> 6, l = t & 63, wr = w >> 1, wc = w & 1;
  f32x4 acc[4][4] = {};
  for (int it = 0; it < 16; ++it) {
    int k0 = it * 32;
#pragma unroll
    for (int c = 0; c < 2; ++c) {
      int u = c * 256 + t; int rr = u >> 2, p = u & 3;
      int sg = p ^ ((rr >> 1) & 3);
      load_lds16(A + (j0 + rr) * 512 + k0 + sg * 8, At + (c * 256 + (t & ~63)) * 8);
      load_lds16(B + (f0 + rr) * 512 + k0 + sg * 8, Bt2 + (c * 256 + (t & ~63)) * 8);
    }
    __syncthreads();
    bf16x8 af[4], bfr[4];
#pragma unroll
    for (int m = 0; m < 4; ++m) {
      int rr = wr * 64 + m * 16 + (l & 15);
      int q = (l >> 4) ^ ((rr >> 1) & 3);
      af[m] = *(const bf16x8*)(At + rr * 32 + q * 8);
    }
#pragma unroll
    for (int n = 0; n < 4; ++n) {
      int rb = wc * 64 + n * 16 + (l & 15);
      int q = (l >> 4) ^ ((rb >> 1) & 3);
      bfr[n] = *(const bf16x8*)(Bt2 + rb * 32 + q * 8);
    }
#pragma unroll
    for (int m = 0; m < 4; ++m)
#pragma unroll
      for (int n = 0; n < 4; ++n)
        acc[m][n] = __builtin_amdgcn_mfma_f32_16x16x32_bf16(af[m], bfr[n], acc[m][n], 0, 0, 0);
    __syncthreads();
  }
#pragma unroll
  for (int m = 0; m < 4; ++m)
#pragma unroll
    for (int n = 0; n < 4; ++n) {
      int j = j0 + wr * 64 + m * 16 + (l >> 4) * 4;
      int f = f0 + wc * 64 + n * 16 + (l & 15);
      ushort4 o;
      o.x = f2bf(acc[m][n][0]); o.y = f2bf(acc[m][n][1]);
      o.z = f2bf(acc[m][n][2]); o.w = f2bf(acc[m][n][3]);
      *(ushort4*)(WhmT + f * 8192 + j) = o;
    }
}

// ---------------------------------------------------------------------------
// Fused attn: grid 1024 = 64 rblk x 16 ksplit, 512 thr, 1 blk/CU (128KB LDS).
// Phase 1: stream mask slice 64x512 (16 int4 upfront/thread), P via tables
//   P = mask ? max(A1_i*E1_j, A2_i*E2_j) : 0, written to LDS in A-frag layout
//   (At16[ks][row][32], xor-swizzled); den partials folded in.
// Phase 2: GEMM num[s] = P_lds @ Whm slice: B dbuf via global_load_lds +
//   counted vmcnt(4), A read from resident LDS, 16 MFMA/body, 2 barriers.
// ---------------------------------------------------------------------------
__global__ __launch_bounds__(512, 2) void attn_fused(
    const int* __restrict__ mask, const float* __restrict__ A1f,
    const float* __restrict__ A2f, const float* __restrict__ E1,
    const float* __restrict__ E2, const ushort* __restrict__ WhmT,
    ushort* __restrict__ num, float* __restrict__ den_part) {
  __shared__ ushort At16[16 * 64 * 32];  // 64 KB: [ks][row][32k] swizzled
  __shared__ ushort Bt[2][512 * 32];     // 64 KB: [f][32k] swizzled, dbuf
  int t = threadIdx.x;
  int bid = blockIdx.x;
  int s = bid & 15, rblk = bid >> 4;
  int i0 = rblk * 64, kb = s * 512;
  int w = t >> 6, l = t & 63, l15 = l & 15, lq = l >> 4;

  // ================= phase 1: P slice -> LDS =================
  {
    int row = t >> 3, g = t & 7;           // row 0..63, g 0..7
    int i = i0 + row;
    float a1 = A1f[i], a2 = A2f[i];
    const int* mrow = mask + (size_t)i * 8192 + kb + g * 8;
    int4 mka[8], mkb[8];
#pragma unroll
    for (int c = 0; c < 8; ++c) {          // all mask loads upfront
      mka[c] = *(const int4*)(mrow + c * 64);
      mkb[c] = *(const int4*)(mrow + c * 64 + 4);
    }
    const float* e1p = E1 + kb + g * 8;
    const float* e2p = E2 + kb + g * 8;
    float dacc = 0.f;
    int qsw = (g & 3) ^ ((row >> 1) & 3);  // swizzle group, const per thread
    ushort* lbase = &At16[0] + row * 32 + qsw * 8;
    // rolling E prefetch (chunk 0 loaded now)
    float4 e1a = *(const float4*)(e1p), e1b = *(const float4*)(e1p + 4);
    float4 e2a = *(const float4*)(e2p), e2b = *(const float4*)(e2p + 4);
#pragma unroll
    for (int c = 0; c < 8; ++c) {
      int4 k0 = mka[c], k1 = mkb[c];
      float4 f1a = e1a, f1b = e1b, f2a = e2a, f2b = e2b;
      if (c < 7) {
        e1a = *(const float4*)(e1p + (c + 1) * 64);
        e1b = *(const float4*)(e1p + (c + 1) * 64 + 4);
        e2a = *(const float4*)(e2p + (c + 1) * 64);
        e2b = *(const float4*)(e2p + (c + 1) * 64 + 4);
      }
      float p0 = k0.x ? fmaxf(a1 * f1a.x, a2 * f2a.x) : 0.f;
      float p1 = k0.y ? fmaxf(a1 * f1a.y, a2 * f2a.y) : 0.f;
      float p2 = k0.z ? fmaxf(a1 * f1a.z, a2 * f2a.z) : 0.f;
      float p3 = k0.w ? fmaxf(a1 * f1a.w, a2 * f2a.w) : 0.f;
      float p4 = k1.x ? fmaxf(a1 * f1b.x, a2 * f2b.x) : 0.f;
      float p5 = k1.y ? fmaxf(a1 * f1b.y, a2 * f2b.y) : 0.f;
      float p6 = k1.z ? fmaxf(a1 * f1b.z, a2 * f2b.z) : 0.f;
      float p7 = k1.w ? fmaxf(a1 * f1b.w, a2 * f2b.w) : 0.f;
      ushort b0 = f2bf(p0), b1 = f2bf(p1), b2 = f2bf(p2), b3 = f2bf(p3);
      ushort b4 = f2bf(p4), b5 = f2bf(p5), b6 = f2bf(p6), b7 = f2bf(p7);
      dacc += ((bf2f(b0) + bf2f(b1)) + (bf2f(b2) + bf2f(b3)))
            + ((bf2f(b4) + bf2f(b5)) + (bf2f(b6) + bf2f(b7)));
      int ks = (g >> 2) + c * 2;           // k-step 0..15
      ushort4 o1; o1.x = b0; o1.y = b1; o1.z = b2; o1.w = b3;
      ushort4 o2; o2.x = b4; o2.y = b5; o2.z = b6; o2.w = b7;
      *(ushort4*)(lbase + ks * 2048) = o1;
      *(ushort4*)(lbase + ks * 2048 + 4) = o2;
    }
    // row-sum partials: reduce across the 8 g-lanes of each row
    dacc += __shfl_xor(dacc, 1, 64);
    dacc += __shfl_xor(dacc, 2, 64);
    dacc += __shfl_xor(dacc, 4, 64);
    if (g == 0) den_part[s * 4096 + i] = dacc;
  }
  __syncthreads();

  // ================= phase 2: GEMM from LDS A + staged B =================
  f32x4 acc[4][4] = {};
  int qA = lq ^ ((l15 >> 1) & 3);
  const ushort* paB = &At16[0] + l15 * 32 + qA * 8;   // + ks*2048 + m*512
  const ushort* pb0 = &Bt[0][0] + (w * 64 + l15) * 32 + qA * 8;
  const ushort* pb1 = &Bt[1][0] + (w * 64 + l15) * 32 + qA * 8;

#define STAGE_B(BUF_, T_)                                                     \
  {                                                                           \
    int k0_ = kb + (T_) * 32;                                                 \
    ushort* bb_ = BUF_;                                                       \
    _Pragma("unroll") for (int c = 0; c < 4; ++c) {                           \
      int u_ = c * 512 + t; int rr_ = u_ >> 2, p_ = u_ & 3;                   \
      int sg_ = p_ ^ ((rr_ >> 1) & 3);                                        \
      load_lds16(WhmT + rr_ * 8192 + k0_ + sg_ * 8,                           \
                 bb_ + (c * 512 + (t & ~63)) * 8);                            \
    }                                                                         \
  }

#define BODY(IT_, PB_, BN_, DO_STAGE, VMC_)                                   \
  {                                                                           \
    if (DO_STAGE) { STAGE_B(BN_, (IT_) + 1); }                                \
    asm volatile("s_waitcnt vmcnt(" #VMC_ ")" ::: "memory");                  \
    __builtin_amdgcn_s_barrier();                                             \
    bf16x8 af[4];                                                             \
    _Pragma("unroll") for (int m = 0; m < 4; ++m)                             \
      af[m] = *(const bf16x8*)(paB + (IT_) * 2048 + m * 512);                 \
    __builtin_amdgcn_s_setprio(1);                                            \
    _Pragma("unroll") for (int n = 0; n < 4; ++n) {                           \
      bf16x8 bfr = *(const bf16x8*)(PB_ + n * 512);                           \
      _Pragma("unroll") for (int m = 0; m < 4; ++m)                           \
        acc[m][n] = __builtin_amdgcn_mfma_f32_16x16x32_bf16(af[m], bfr,       \
                                                            acc[m][n], 0, 0, 0); \
    }                                                                         \
    __builtin_amdgcn_s_setprio(0);                                            \
    asm volatile("s_barrier" ::: "memory");                                   \
  }

  STAGE_B(&Bt[0][0], 0);
  for (int it2 = 0; it2 < 7; ++it2) {
    BODY(it2 * 2,     pb0, &Bt[1][0], true, 4);
    BODY(it2 * 2 + 1, pb1, &Bt[0][0], true, 4);
  }
  BODY(14, pb0, &Bt[1][0], true, 4);
  BODY(15, pb1, &Bt[0][0], false, 0);

  // numerator write, packed [s][i>>2][512][i&3] bf16, 8B/lane full lines
#pragma unroll
  for (int m = 0; m < 4; ++m)
#pragma unroll
    for (int n = 0; n < 4; ++n) {
      int ig = rblk * 16 + m * 4 + lq;
      int f = w * 64 + n * 16 + l15;
      ushort4 o;
      o.x = f2bf(acc[m][n][0]); o.y = f2bf(acc[m][n][1]);
      o.z = f2bf(acc[m][n][2]); o.w = f2bf(acc[m][n][3]);
      *(ushort4*)(num + (((size_t)s * 1024 + ig) * 512 + f) * 4) = o;
    }
#undef BODY
#undef STAGE_B
}

// den[i] = sum of 16 ksplit partials
__global__ void p_den(const float* __restrict__ den_part, float* __restrict__ den) {
  int i = blockIdx.x * 256 + threadIdx.x;  // 4096
  float d = 0.f;
#pragma unroll
  for (int k = 0; k < 16; ++k) d += den_part[k * 4096 + i];
  den[i] = d;
}

// out[ig*4+r][f] = (sum_s num[s][ig][f][r]) / den[ig*4+r]
__global__ void reduce_out(const ushort* __restrict__ num, const float* __restrict__ den,
                           float* __restrict__ out) {
  int idx = blockIdx.x * 256 + threadIdx.x;  // 524288 threads
  int ig = idx >> 9, f = idx & 511;
  float s0 = 0.f, s1 = 0.f, s2 = 0.f, s3 = 0.f;
#pragma unroll
  for (int s = 0; s < 16; ++s) {
    ushort4 v = *(const ushort4*)(num + (((size_t)s * 1024 + ig) * 512 + f) * 4);
    s0 += bf2f(v.x); s1 += bf2f(v.y); s2 += bf2f(v.z); s3 += bf2f(v.w);
  }
  const float* dp = den + ig * 4;
  float* op = out + (size_t)ig * 4 * 512 + f;
  op[0]       = s0 / dp[0];
  op[512]     = s1 / dp[1];
  op[2 * 512] = s2 / dp[2];
  op[3 * 512] = s3 / dp[3];
}

extern "C" void kernel_launch(void* const* d_in, const int* in_sizes, int n_in,
                              void* d_out, int out_size, void* d_ws, size_t ws_size,
                              hipStream_t stream) {
  const float* node   = (const float*)d_in[0];
  const float* neigh  = (const float*)d_in[1];
  const float* weight = (const float*)d_in[2];
  const float* att    = (const float*)d_in[3];
  const int*   mask   = (const int*)d_in[4];
  float* out = (float*)d_out;

  char* ws = (char*)d_ws;                     // needs ~88 MB
  float* fb = (float*)ws;
  float* w_a1    = fb;              // 512
  float* w_a2    = fb + 512;        // 512
  float* s_n     = fb + 1024;       // 4096
  float* s_m     = fb + 5120;       // 8192
  float* smax    = fb + 13312;      // 1 (pad 8)
  float* A1      = fb + 13320;      // 4096
  float* A2      = fb + 17416;      // 4096
  float* E1      = fb + 21512;      // 8192
  float* E2      = fb + 29704;      // 8192
  float* den_part= fb + 37896;      // 65536 (16 x 4096)
  float* den     = fb + 103432;     // 4096
  ushort* wT_bf  = (ushort*)(ws + 512 * 1024);        // 0.5 MB
  ushort* WhmT   = (ushort*)(ws + 1 * 1024 * 1024);   // 8 MB
  ushort* num    = (ushort*)(ws + 9 * 1024 * 1024);   // 64 MB (16 slices)
  ushort* neigh_bf = (ushort*)(ws + 73 * 1024 * 1024); // 8 MB scratch

  rowdot<<<128, 256, 0, stream>>>(weight, att, w_a1);
  rowdot<<<128, 256, 0, stream>>>(weight, att + 512, w_a2);
  rowdot<<<1024, 256, 0, stream>>>(node, w_a1, s_n);
  rowdot<<<2048, 256, 0, stream>>>(neigh, w_a2, s_m);
  reduce_max<<<1, 256, 0, stream>>>(s_m, smax);
  exp_sm<<<32, 256, 0, stream>>>(s_m, E1, E2);
  comp_A<<<16, 256, 0, stream>>>(s_n, smax, A1, A2);
  cvt4_bf16<<<4096, 256, 0, stream>>>(neigh, neigh_bf);
  transpose_w<<<256, 256, 0, stream>>>(weight, wT_bf);
  gemm_whmT<<<256, 256, 0, stream>>>(neigh_bf, wT_bf, WhmT);
  attn_fused<<<1024, 512, 0, stream>>>(mask, A1, A2, E1, E2, WhmT, num, den_part);
  p_den<<<16, 256, 0, stream>>>(den_part, den);
  reduce_out<<<2048, 256, 0, stream>>>(num, den, out);
}